// Round 10
// baseline (129.100 us; speedup 1.0000x reference)
//
#include <hip/hip_runtime.h>
#include <math.h>

// Problem constants (from reference setup_inputs)
static constexpr int N_ = 4, R_ = 256, C_ = 1024, H_ = 50, W_ = 50, P_ = 7;
static constexpr int HW_ = H_ * W_;
static constexpr int PP_ = P_ * P_;            // 49 output pixels per (roi, channel)
static constexpr int CH_ = 64;                 // channels per wave; 16 waves per roi
static constexpr int FM_WORDS = N_ * C_ * HW_; // 10,240,000
static constexpr int RW_ = 20;                 // LDS patch row stride (words)
static constexpr int PW_ = 16 * RW_;           // 320 words per patch

typedef const __attribute__((address_space(1))) void* gaddr_t;
typedef __attribute__((address_space(3))) void* laddr_t;

__device__ __forceinline__ void ld_lds16(const float* g, float* l) {
    __builtin_amdgcn_global_load_lds((gaddr_t)g, (laddr_t)l, 16, 0, 0);
}
__device__ __forceinline__ void ld_lds4(const float* g, float* l) {
    __builtin_amdgcn_global_load_lds((gaddr_t)g, (laddr_t)l, 4, 0, 0);
}

// Counted wait (T4): at each consume point there are exactly 6 staging loads
// (3 STAGEs x 2) newer than the waited STAGE, plus <=3 interleaved stores.
// vmcnt(6) guarantees the waited STAGE retired whether or not stores count
// (vmcnt retires in issue order, m135).
#define VMWAIT6()  asm volatile("s_waitcnt vmcnt(6)" ::: "memory")
#define LGKMWAIT() asm volatile("s_waitcnt lgkmcnt(0)" ::: "memory")

// Per-axis geometry (absolute indices; zero-padding folded into weights).
// Sample spacing < 1 px => both sub-samples' corners lie in a 3-wide window.
__device__ __forceinline__ void axis_rel(float p0, float p1, int base, int L,
                                         int& rel0, float wA[3], float wB[3]) {
    float f0 = floorf(p0); int i0 = (int)f0; float a0 = p0 - f0;
    float f1 = floorf(p1); int i1 = (int)f1; float a1 = p1 - f1;
    const bool o = (i1 > i0);
    wA[0] = 1.0f - a0; wA[1] = a0; wA[2] = 0.0f;
    wB[0] = o ? 0.0f : (1.0f - a1);
    wB[1] = o ? (1.0f - a1) : a1;
    wB[2] = o ? a1 : 0.0f;
#pragma unroll
    for (int j = 0; j < 3; ++j) {
        int ij = i0 + j;
        if (ij < 0 || ij > L - 1) { wA[j] = 0.0f; wB[j] = 0.0f; }
    }
    rel0 = min(max(i0 - base, 0), 13);   // window-relative; dy,dx in [0,15]
}

// 9 LDS reads at COMPILE-TIME offsets from one per-lane base -> LLVM's DS
// combiner merges const-offset b32 pairs into ds_read2_b32 (5 DS instrs).
// Row stride 20: bank(20r+c) cycles 8 distinct values over rows -> the
// stride-16 vertical bank resonance of the linear layout stays broken.
__device__ __forceinline__ float gather9(const float* __restrict__ g,
                                         const float wyA[3], const float wyB[3],
                                         const float wxA[3], const float wxB[3]) {
    const float v00 = g[0],       v01 = g[1],       v02 = g[2];
    const float v10 = g[RW_],     v11 = g[RW_ + 1], v12 = g[RW_ + 2];
    const float v20 = g[2 * RW_], v21 = g[2 * RW_ + 1], v22 = g[2 * RW_ + 2];

    const float tA0 = fmaf(wyA[2], v20, fmaf(wyA[1], v10, wyA[0] * v00));
    const float tA1 = fmaf(wyA[2], v21, fmaf(wyA[1], v11, wyA[0] * v01));
    const float tA2 = fmaf(wyA[2], v22, fmaf(wyA[1], v12, wyA[0] * v02));
    const float tB0 = fmaf(wyB[2], v20, fmaf(wyB[1], v10, wyB[0] * v00));
    const float tB1 = fmaf(wyB[2], v21, fmaf(wyB[1], v11, wyB[0] * v01));
    const float tB2 = fmaf(wyB[2], v22, fmaf(wyB[1], v12, wyB[0] * v02));

    const float s00 = fmaf(wxA[2], tA2, fmaf(wxA[1], tA1, wxA[0] * tA0));
    const float s01 = fmaf(wxB[2], tA2, fmaf(wxB[1], tA1, wxB[0] * tA0));
    const float s10 = fmaf(wxA[2], tB2, fmaf(wxA[1], tB1, wxA[0] * tB0));
    const float s11 = fmaf(wxB[2], tB2, fmaf(wxB[1], tB1, wxB[0] * tB0));

    return fmaxf(fmaxf(s00, s01), fmaxf(s10, s11));
}

// Block = 4 waves. Grid = N*R*4. Block (nr, q); wave w -> channels (q*4+w)*64..+63.
// Lane = output pixel (49 active / 64). Per-wave 4-deep LDS ring; single-wave
// producer==consumer => counted vmcnt/lgkmcnt, no barriers.
__global__ __launch_bounds__(256) void roipool_kernel(
    const float* __restrict__ rois,
    const float* __restrict__ fm,
    float* __restrict__ out) {

    __shared__ float patch[4][4][PW_];   // [wave][ring][16 x 20 words], 20 KB

    const int b  = blockIdx.x;
    const int q  = b & 3;
    const int nr = b >> 2;               // n*R + r
    const int n  = nr >> 8;              // R_ = 256
    const int lane = threadIdx.x & 63;
    const int wv = __builtin_amdgcn_readfirstlane(threadIdx.x >> 6);
    const int c0 = (q * 4 + wv) * CH_;

    // roi: (y, x, h, w) image coords; stride 16
    const float4 roi = reinterpret_cast<const float4*>(rois)[nr];
    const float y1 = roi.x * 0.0625f;
    const float x1 = roi.y * 0.0625f;
    const float y2 = (roi.x + roi.z) * 0.0625f;
    const float x2 = (roi.y + roi.w) * 0.0625f;
    const float sy = (y2 - y1) * (1.0f / 13.0f);
    const float sx = (x2 - x1) * (1.0f / 13.0f);

    const int y0 = max((int)floorf(y1), 0);   // window origin
    const int x0 = max((int)floorf(x1), 0);

    // Staging sources. Patch layout: word w -> row w/20, col w%20; cols 16..19
    // are pad (never read, garbage OK). Cols beyond the plane row wrap into the
    // next row (zero weight); rows beyond 49 clamp (zero weight).
    // instr1 (width 16): lane stages words 4*lane .. 4*lane+3 (chunks never
    // straddle rows since 20 % 4 == 0; pad chunk col==16 -> row start).
    const int w1 = 4 * lane;
    const int r1 = w1 / RW_, c1 = w1 % RW_;
    const int src1 = min(y0 + r1, H_ - 1) * W_ + x0 + ((c1 >= 16) ? 0 : c1);
    // instr2 (width 4): lane stages word 256+lane (rows 12..15).
    const int w2 = 256 + lane;
    const int r2 = w2 / RW_, c2 = w2 % RW_;
    const int src2 = min(y0 + r2, H_ - 1) * W_ + x0 + ((c2 >= 16) ? 0 : c2);

    int pi = lane / 7;
    int pj = lane - pi * 7;
    const bool active = lane < PP_;
    if (!active) { pi = 0; pj = 0; }     // idle lanes mirror lane 0 -> broadcast

    const float py0 = y1 + sy * (float)(2 * pi);
    const float py1 = y1 + sy * (float)(2 * pi + 1);
    const float px0 = x1 + sx * (float)(2 * pj);
    const float px1 = x1 + sx * (float)(2 * pj + 1);

    int ryr; float wyA[3], wyB[3];
    axis_rel(py0, py1, y0, H_, ryr, wyA, wyB);
    int cxr; float wxA[3], wxB[3];
    axis_rel(px0, px1, x0, W_, cxr, wxA, wxB);
    const int gb = ryr * RW_ + cxr;      // per-lane base; max 273+42=315 < 320

    const int pw0 = (n * C_ + c0) * HW_; // absolute word offset of ch c0
    float* __restrict__ po = out + ((size_t)nr * C_ + c0) * PP_ + lane;

    float* const s0 = &patch[wv][0][0];
    float* const s1 = &patch[wv][1][0];
    float* const s2 = &patch[wv][2][0];
    float* const s3 = &patch[wv][3][0];

#define STAGE(BUF, KK) do { \
        const int p_ = pw0 + (KK) * HW_; \
        ld_lds16(fm + min(p_ + src1, FM_WORDS - 4), (BUF)); \
        ld_lds4 (fm + min(p_ + src2, FM_WORDS - 1), (BUF) + 256); \
    } while (0)

    STAGE(s0, 0);
    STAGE(s1, 1);
    STAGE(s2, 2);
    STAGE(s3, 3);

    for (int k = 0; k < CH_; k += 4) {
        VMWAIT6();
        const float r0 = gather9(s0 + gb, wyA, wyB, wxA, wxB);
        if (active) po[k * PP_] = r0;
        LGKMWAIT();
        STAGE(s0, min(k + 4, CH_ - 1));  // tail: dummy restage, uniform vmcnt

        VMWAIT6();
        const float r1 = gather9(s1 + gb, wyA, wyB, wxA, wxB);
        if (active) po[(k + 1) * PP_] = r1;
        LGKMWAIT();
        STAGE(s1, min(k + 5, CH_ - 1));

        VMWAIT6();
        const float r2 = gather9(s2 + gb, wyA, wyB, wxA, wxB);
        if (active) po[(k + 2) * PP_] = r2;
        LGKMWAIT();
        STAGE(s2, min(k + 6, CH_ - 1));

        VMWAIT6();
        const float r3 = gather9(s3 + gb, wyA, wyB, wxA, wxB);
        if (active) po[(k + 3) * PP_] = r3;
        LGKMWAIT();
        STAGE(s3, min(k + 7, CH_ - 1));
    }
#undef STAGE
}

extern "C" void kernel_launch(void* const* d_in, const int* in_sizes, int n_in,
                              void* d_out, int out_size, void* d_ws, size_t ws_size,
                              hipStream_t stream) {
    const float* rois = (const float*)d_in[0];        // [4,256,4]
    const float* fm   = (const float*)d_in[1];        // [4,1024,50,50]
    float* out        = (float*)d_out;                // [4,256,1024,7,7]

    const int blocks = N_ * R_ * 4;                   // 4096
    roipool_kernel<<<blocks, 256, 0, stream>>>(rois, fm, out);
}

// Round 11
// 116.447 us; speedup vs baseline: 1.1087x; 1.1087x over previous
//
#include <hip/hip_runtime.h>
#include <math.h>

// Problem constants (from reference setup_inputs)
static constexpr int N_ = 4, R_ = 256, C_ = 1024, H_ = 50, W_ = 50, P_ = 7;
static constexpr int HW_ = H_ * W_;            // 2500 words per plane
static constexpr int PP_ = P_ * P_;            // 49 output pixels per (roi, channel)
static constexpr int CHB_ = 4;                 // channels per block (= waves)
static constexpr int PLW_ = 2816;              // LDS plane stride: >= 2602 readable, 11*256 staged
static constexpr int FM_WORDS = N_ * C_ * HW_; // 10,240,000

typedef const __attribute__((address_space(1))) void* gaddr_t;
typedef __attribute__((address_space(3))) void* laddr_t;

__device__ __forceinline__ void ld_lds16(const float* g, float* l) {
    // async global->LDS DMA, 16B/lane; dest = wave-uniform base + lane*16B
    __builtin_amdgcn_global_load_lds((gaddr_t)g, (laddr_t)l, 16, 0, 0);
}

// Per-axis geometry, ABSOLUTE indices. rois >= 0 => p0 >= 0 => i0 >= 0 (no
// left clamp needed). Zero-padding validity folded into weights; i0 clamped
// <= L-1 so LDS addresses stay <= 2499+102, all staged (finite) words.
__device__ __forceinline__ void axis_w(float p0, float p1, int L,
                                       int& i0c, float wA[3], float wB[3]) {
    float f0 = floorf(p0); int i0 = (int)f0; float a0 = p0 - f0;
    float f1 = floorf(p1); int i1 = (int)f1; float a1 = p1 - f1;
    const bool o = (i1 > i0);
    wA[0] = 1.0f - a0; wA[1] = a0; wA[2] = 0.0f;
    wB[0] = o ? 0.0f : (1.0f - a1);
    wB[1] = o ? (1.0f - a1) : a1;
    wB[2] = o ? a1 : 0.0f;
#pragma unroll
    for (int j = 0; j < 3; ++j) {
        int ij = i0 + j;
        if (ij > L - 1) { wA[j] = 0.0f; wB[j] = 0.0f; }
    }
    i0c = min(max(i0, 0), L - 1);
}

// 9 LDS reads at compile-time offsets {0,1,2,50,51,52,100,101,102} from one
// per-lane base -> LLVM merges const-offset pairs into ds_read2_b32 (5 instrs).
__device__ __forceinline__ float gather9(const float* __restrict__ g,
                                         const float wyA[3], const float wyB[3],
                                         const float wxA[3], const float wxB[3]) {
    const float v00 = g[0],       v01 = g[1],        v02 = g[2];
    const float v10 = g[W_],      v11 = g[W_ + 1],   v12 = g[W_ + 2];
    const float v20 = g[2 * W_],  v21 = g[2 * W_ + 1], v22 = g[2 * W_ + 2];

    const float tA0 = fmaf(wyA[2], v20, fmaf(wyA[1], v10, wyA[0] * v00));
    const float tA1 = fmaf(wyA[2], v21, fmaf(wyA[1], v11, wyA[0] * v01));
    const float tA2 = fmaf(wyA[2], v22, fmaf(wyA[1], v12, wyA[0] * v02));
    const float tB0 = fmaf(wyB[2], v20, fmaf(wyB[1], v10, wyB[0] * v00));
    const float tB1 = fmaf(wyB[2], v21, fmaf(wyB[1], v11, wyB[0] * v01));
    const float tB2 = fmaf(wyB[2], v22, fmaf(wyB[1], v12, wyB[0] * v02));

    const float s00 = fmaf(wxA[2], tA2, fmaf(wxA[1], tA1, wxA[0] * tA0));
    const float s01 = fmaf(wxB[2], tA2, fmaf(wxB[1], tA1, wxB[0] * tA0));
    const float s10 = fmaf(wxA[2], tB2, fmaf(wxA[1], tB1, wxA[0] * tB0));
    const float s11 = fmaf(wxB[2], tB2, fmaf(wxB[1], tB1, wxB[0] * tB0));

    return fmaxf(fmaxf(s00, s01), fmaxf(s10, s11));
}

// PLANE-RESIDENT: block = (image n, channel-group of 4). Stage the 4 full
// 50x50 planes into LDS once (wave w stages plane w), then serve ALL 256
// ROIs from LDS: wave w handles rois w, w+4, ...; lane = output pixel.
// Geometry per roi amortizes over 4 channels; K-loop has zero VMEM waits.
__global__ __launch_bounds__(256) void roipool_kernel(
    const float* __restrict__ rois,
    const float* __restrict__ fm,
    float* __restrict__ out) {

    __shared__ float planes[CHB_][PLW_];      // 45 KB -> 3 blocks/CU

    const int b  = blockIdx.x;                // grid = N_ * 256
    const int n  = b >> 8;
    const int c0 = (b & 255) * CHB_;
    const int lane = threadIdx.x & 63;
    const int wv = __builtin_amdgcn_readfirstlane(threadIdx.x >> 6);

    // ---- stage plane (c0 + wv) : 11 x width-16 DMA, then one barrier ----
    {
        const int base = (n * C_ + c0 + wv) * HW_;
        float* dst = &planes[wv][0];
#pragma unroll
        for (int t = 0; t < 11; ++t) {
            const int src = min(base + t * 256 + lane * 4, FM_WORDS - 4);
            ld_lds16(fm + src, dst + t * 256);
        }
    }
    asm volatile("s_waitcnt vmcnt(0)" ::: "memory");
    __syncthreads();

    int pi = lane / 7;
    int pj = lane - pi * 7;
    const bool active = lane < PP_;
    if (!active) { pi = 0; pj = 0; }          // idle lanes mirror lane 0

    const float* const p0l = &planes[0][0];
    const float* const p1l = &planes[1][0];
    const float* const p2l = &planes[2][0];
    const float* const p3l = &planes[3][0];

    const size_t obase = ((size_t)n * R_ * C_ + c0) * PP_ + lane;

    for (int r = wv; r < R_; r += CHB_) {
        const float4 roi = reinterpret_cast<const float4*>(rois)[n * R_ + r];
        const float y1 = roi.x * 0.0625f;
        const float x1 = roi.y * 0.0625f;
        const float y2 = (roi.x + roi.z) * 0.0625f;
        const float x2 = (roi.y + roi.w) * 0.0625f;
        const float sy = (y2 - y1) * (1.0f / 13.0f);
        const float sx = (x2 - x1) * (1.0f / 13.0f);

        const float py0 = y1 + sy * (float)(2 * pi);
        const float py1 = y1 + sy * (float)(2 * pi + 1);
        const float px0 = x1 + sx * (float)(2 * pj);
        const float px1 = x1 + sx * (float)(2 * pj + 1);

        int iy0; float wyA[3], wyB[3];
        axis_w(py0, py1, H_, iy0, wyA, wyB);
        int ix0; float wxA[3], wxB[3];
        axis_w(px0, px1, W_, ix0, wxA, wxB);
        const int gb = iy0 * W_ + ix0;        // <= 2499; reads reach <= 2601 (staged)

        const float r0 = gather9(p0l + gb, wyA, wyB, wxA, wxB);
        const float r1 = gather9(p1l + gb, wyA, wyB, wxA, wxB);
        const float r2 = gather9(p2l + gb, wyA, wyB, wxA, wxB);
        const float r3 = gather9(p3l + gb, wyA, wyB, wxA, wxB);

        if (active) {
            float* __restrict__ po = out + obase + (size_t)r * C_ * PP_;
            po[0]       = r0;
            po[PP_]     = r1;
            po[2 * PP_] = r2;
            po[3 * PP_] = r3;
        }
    }
}

extern "C" void kernel_launch(void* const* d_in, const int* in_sizes, int n_in,
                              void* d_out, int out_size, void* d_ws, size_t ws_size,
                              hipStream_t stream) {
    const float* rois = (const float*)d_in[0];        // [4,256,4]
    const float* fm   = (const float*)d_in[1];        // [4,1024,50,50]
    float* out        = (float*)d_out;                // [4,256,1024,7,7]

    const int blocks = N_ * (C_ / CHB_);              // 4 * 256 = 1024
    roipool_kernel<<<blocks, 256, 0, stream>>>(rois, fm, out);
}

// Round 12
// 84.009 us; speedup vs baseline: 1.5367x; 1.3861x over previous
//
#include <hip/hip_runtime.h>
#include <math.h>

// Problem constants (from reference setup_inputs)
static constexpr int N_ = 4, R_ = 256, C_ = 1024, H_ = 50, W_ = 50, P_ = 7;
static constexpr int HW_ = H_ * W_;            // 2500 words per plane
static constexpr int PP_ = P_ * P_;            // 49 output pixels per (roi, channel)
static constexpr int CHB_ = 4;                 // channels (planes) per block
static constexpr int WVS_ = 8;                 // waves per block (512 threads)
static constexpr int PLW_ = 2816;              // LDS plane stride (11*256 staged)
static constexpr int FM_WORDS = N_ * C_ * HW_; // 10,240,000

typedef const __attribute__((address_space(1))) void* gaddr_t;
typedef __attribute__((address_space(3))) void* laddr_t;

__device__ __forceinline__ void ld_lds16(const float* g, float* l) {
    // async global->LDS DMA, 16B/lane; dest = wave-uniform base + lane*16B
    __builtin_amdgcn_global_load_lds((gaddr_t)g, (laddr_t)l, 16, 0, 0);
}

// Per-axis geometry, ABSOLUTE indices. rois >= 0 => i0 >= 0 (no left clamp).
// Zero-padding validity folded into weights; i0 clamped <= L-1 so LDS reads
// stay <= 2499+102 < 2816, all staged (finite) words.
__device__ __forceinline__ void axis_w(float p0, float p1, int L,
                                       int& i0c, float wA[3], float wB[3]) {
    float f0 = floorf(p0); int i0 = (int)f0; float a0 = p0 - f0;
    float f1 = floorf(p1); int i1 = (int)f1; float a1 = p1 - f1;
    const bool o = (i1 > i0);
    wA[0] = 1.0f - a0; wA[1] = a0; wA[2] = 0.0f;
    wB[0] = o ? 0.0f : (1.0f - a1);
    wB[1] = o ? (1.0f - a1) : a1;
    wB[2] = o ? a1 : 0.0f;
#pragma unroll
    for (int j = 0; j < 3; ++j) {
        int ij = i0 + j;
        if (ij > L - 1) { wA[j] = 0.0f; wB[j] = 0.0f; }
    }
    i0c = min(max(i0, 0), L - 1);
}

// 9 LDS reads at compile-time offsets {0,1,2,50,51,52,100,101,102} from one
// per-lane base -> LLVM merges const-offset pairs into ds_read2_b32 (5 instrs).
__device__ __forceinline__ float gather9(const float* __restrict__ g,
                                         const float wyA[3], const float wyB[3],
                                         const float wxA[3], const float wxB[3]) {
    const float v00 = g[0],       v01 = g[1],          v02 = g[2];
    const float v10 = g[W_],      v11 = g[W_ + 1],     v12 = g[W_ + 2];
    const float v20 = g[2 * W_],  v21 = g[2 * W_ + 1], v22 = g[2 * W_ + 2];

    const float tA0 = fmaf(wyA[2], v20, fmaf(wyA[1], v10, wyA[0] * v00));
    const float tA1 = fmaf(wyA[2], v21, fmaf(wyA[1], v11, wyA[0] * v01));
    const float tA2 = fmaf(wyA[2], v22, fmaf(wyA[1], v12, wyA[0] * v02));
    const float tB0 = fmaf(wyB[2], v20, fmaf(wyB[1], v10, wyB[0] * v00));
    const float tB1 = fmaf(wyB[2], v21, fmaf(wyB[1], v11, wyB[0] * v01));
    const float tB2 = fmaf(wyB[2], v22, fmaf(wyB[1], v12, wyB[0] * v02));

    const float s00 = fmaf(wxA[2], tA2, fmaf(wxA[1], tA1, wxA[0] * tA0));
    const float s01 = fmaf(wxB[2], tA2, fmaf(wxB[1], tA1, wxB[0] * tA0));
    const float s10 = fmaf(wxA[2], tB2, fmaf(wxA[1], tB1, wxA[0] * tB0));
    const float s11 = fmaf(wxB[2], tB2, fmaf(wxB[1], tB1, wxB[0] * tB0));

    return fmaxf(fmaxf(s00, s01), fmaxf(s10, s11));
}

// PLANE-RESIDENT, 8 waves: block = (image n, channel-group of 4). The 8 waves
// cooperatively stage the 4 full 50x50 planes into LDS (half-plane each), then
// all 8 waves serve the 256 ROIs (wave w -> rois w, w+8, ...; lane = pixel;
// each ROI's geometry amortized over the 4 channels). K-loop is VMEM-wait-free.
// 512 threads raises waves/SIMD 3 -> 6 to cover DS latency (r11: occupancy 24%
// with VALU 56% / DS ~64% and nothing saturated = latency-bound).
__global__ __launch_bounds__(512) void roipool_kernel(
    const float* __restrict__ rois,
    const float* __restrict__ fm,
    float* __restrict__ out) {

    __shared__ float planes[CHB_][PLW_];      // 45 KB -> 3 blocks/CU (LDS-bound)

    const int b  = blockIdx.x;                // grid = N_ * 256
    const int n  = b >> 8;
    const int c0 = (b & 255) * CHB_;
    const int lane = threadIdx.x & 63;
    const int wv = __builtin_amdgcn_readfirstlane(threadIdx.x >> 6);

    // ---- stage: wave w covers plane w>>1, chunk range (w&1 ? 6..10 : 0..5) --
    {
        const int pl = wv >> 1;
        const int h  = wv & 1;
        const int base = (n * C_ + c0 + pl) * HW_;
        float* dst = &planes[pl][0];
        const int t0 = h * 6, t1 = h ? 11 : 6;
        for (int t = t0; t < t1; ++t) {
            const int src = min(base + t * 256 + lane * 4, FM_WORDS - 4);
            ld_lds16(fm + src, dst + t * 256);
        }
    }
    asm volatile("s_waitcnt vmcnt(0)" ::: "memory");
    __syncthreads();

    int pi = lane / 7;
    int pj = lane - pi * 7;
    const bool active = lane < PP_;
    if (!active) { pi = 0; pj = 0; }          // idle lanes mirror lane 0

    const float* const p0l = &planes[0][0];
    const float* const p1l = &planes[1][0];
    const float* const p2l = &planes[2][0];
    const float* const p3l = &planes[3][0];

    const size_t obase = ((size_t)n * R_ * C_ + c0) * PP_ + lane;

    for (int r = wv; r < R_; r += WVS_) {
        const float4 roi = reinterpret_cast<const float4*>(rois)[n * R_ + r];
        const float y1 = roi.x * 0.0625f;
        const float x1 = roi.y * 0.0625f;
        const float y2 = (roi.x + roi.z) * 0.0625f;
        const float x2 = (roi.y + roi.w) * 0.0625f;
        const float sy = (y2 - y1) * (1.0f / 13.0f);
        const float sx = (x2 - x1) * (1.0f / 13.0f);

        const float py0 = y1 + sy * (float)(2 * pi);
        const float py1 = y1 + sy * (float)(2 * pi + 1);
        const float px0 = x1 + sx * (float)(2 * pj);
        const float px1 = x1 + sx * (float)(2 * pj + 1);

        int iy0; float wyA[3], wyB[3];
        axis_w(py0, py1, H_, iy0, wyA, wyB);
        int ix0; float wxA[3], wxB[3];
        axis_w(px0, px1, W_, ix0, wxA, wxB);
        const int gb = iy0 * W_ + ix0;        // <= 2499; reads reach <= 2601

        const float r0 = gather9(p0l + gb, wyA, wyB, wxA, wxB);
        const float r1 = gather9(p1l + gb, wyA, wyB, wxA, wxB);
        const float r2 = gather9(p2l + gb, wyA, wyB, wxA, wxB);
        const float r3 = gather9(p3l + gb, wyA, wyB, wxA, wxB);

        if (active) {
            float* __restrict__ po = out + obase + (size_t)r * C_ * PP_;
            po[0]       = r0;
            po[PP_]     = r1;
            po[2 * PP_] = r2;
            po[3 * PP_] = r3;
        }
    }
}

extern "C" void kernel_launch(void* const* d_in, const int* in_sizes, int n_in,
                              void* d_out, int out_size, void* d_ws, size_t ws_size,
                              hipStream_t stream) {
    const float* rois = (const float*)d_in[0];        // [4,256,4]
    const float* fm   = (const float*)d_in[1];        // [4,1024,50,50]
    float* out        = (float*)d_out;                // [4,256,1024,7,7]

    const int blocks = N_ * (C_ / CHB_);              // 4 * 256 = 1024
    roipool_kernel<<<blocks, 512, 0, stream>>>(rois, fm, out);
}

// Round 13
// 78.769 us; speedup vs baseline: 1.6390x; 1.0665x over previous
//
#include <hip/hip_runtime.h>
#include <math.h>

// Problem constants (from reference setup_inputs)
static constexpr int N_ = 4, R_ = 256, C_ = 1024, H_ = 50, W_ = 50, P_ = 7;
static constexpr int HW_ = H_ * W_;            // 2500 words per plane
static constexpr int PP_ = P_ * P_;            // 49 output pixels per (roi, channel)
static constexpr int CHB_ = 4;                 // channels (planes) per block
static constexpr int WVS_ = 16;                // waves per block (1024 threads)
static constexpr int PLW_ = 2816;              // LDS plane stride (11*256 staged)
static constexpr int FM_WORDS = N_ * C_ * HW_; // 10,240,000

typedef const __attribute__((address_space(1))) void* gaddr_t;
typedef __attribute__((address_space(3))) void* laddr_t;

__device__ __forceinline__ void ld_lds16(const float* g, float* l) {
    // async global->LDS DMA, 16B/lane; dest = wave-uniform base + lane*16B
    __builtin_amdgcn_global_load_lds((gaddr_t)g, (laddr_t)l, 16, 0, 0);
}

// Per-axis geometry, ABSOLUTE indices. rois >= 0 => i0 >= 0 (no left clamp).
// Zero-padding validity folded into weights; i0 clamped <= L-1 so LDS reads
// stay <= 2499+102 < 2816, all staged (finite) words.
// A-sub-sample corners span rows/cols {0,1} ONLY: wA has 2 entries (the old
// wA[2] was identically zero -> its FMAs were dead work, now pruned).
__device__ __forceinline__ void axis_w(float p0, float p1, int L,
                                       int& i0c, float wA[2], float wB[3]) {
    float f0 = floorf(p0); int i0 = (int)f0; float a0 = p0 - f0;
    float f1 = floorf(p1); int i1 = (int)f1; float a1 = p1 - f1;
    const bool o = (i1 > i0);
    wA[0] = 1.0f - a0; wA[1] = a0;
    wB[0] = o ? 0.0f : (1.0f - a1);
    wB[1] = o ? (1.0f - a1) : a1;
    wB[2] = o ? a1 : 0.0f;
    if (i0 > L - 1)     { wA[0] = 0.0f; wB[0] = 0.0f; }
    if (i0 + 1 > L - 1) { wA[1] = 0.0f; wB[1] = 0.0f; }
    if (i0 + 2 > L - 1) {               wB[2] = 0.0f; }
    i0c = min(max(i0, 0), L - 1);
}

// 9 LDS reads at compile-time offsets {0,1,2,50,51,52,100,101,102} from one
// per-lane base -> LLVM merges const-offset pairs into ds_read2_b32.
// Pruned reduce: tA (x-sample pair A's row combine) uses rows 0,1 only;
// s00/s10 use cols 0,1 only. 25 VALU ops/channel (was 33).
__device__ __forceinline__ float gather9(const float* __restrict__ g,
                                         const float wyA[2], const float wyB[3],
                                         const float wxA[2], const float wxB[3]) {
    const float v00 = g[0],       v01 = g[1],          v02 = g[2];
    const float v10 = g[W_],      v11 = g[W_ + 1],     v12 = g[W_ + 2];
    const float v20 = g[2 * W_],  v21 = g[2 * W_ + 1], v22 = g[2 * W_ + 2];

    const float tA0 = fmaf(wyA[1], v10, wyA[0] * v00);
    const float tA1 = fmaf(wyA[1], v11, wyA[0] * v01);
    const float tA2 = fmaf(wyA[1], v12, wyA[0] * v02);
    const float tB0 = fmaf(wyB[2], v20, fmaf(wyB[1], v10, wyB[0] * v00));
    const float tB1 = fmaf(wyB[2], v21, fmaf(wyB[1], v11, wyB[0] * v01));
    const float tB2 = fmaf(wyB[2], v22, fmaf(wyB[1], v12, wyB[0] * v02));

    const float s00 = fmaf(wxA[1], tA1, wxA[0] * tA0);
    const float s01 = fmaf(wxB[2], tA2, fmaf(wxB[1], tA1, wxB[0] * tA0));
    const float s10 = fmaf(wxA[1], tB1, wxA[0] * tB0);
    const float s11 = fmaf(wxB[2], tB2, fmaf(wxB[1], tB1, wxB[0] * tB0));

    return fmaxf(fmaxf(s00, s01), fmaxf(s10, s11));
}

// PLANE-RESIDENT, 16 waves (1024 threads): block = (image n, 4 channels).
// The 16 waves cooperatively stage the 4 full 50x50 planes into LDS (wave w:
// plane w>>2, chunk-quarter w&3), then all 16 waves serve the 256 ROIs
// (wave w -> rois w, w+16, ...; lane = output pixel; geometry amortized over
// the 4 channels). K-loop is VMEM-wait-free. 45KB LDS -> 2 blocks/CU = 32
// waves/CU = 8 waves/SIMD (occupancy cap) to cover DS latency.
__global__ __launch_bounds__(1024) void roipool_kernel(
    const float* __restrict__ rois,
    const float* __restrict__ fm,
    float* __restrict__ out) {

    __shared__ float planes[CHB_][PLW_];      // 45 KB

    const int b  = blockIdx.x;                // grid = N_ * 256
    const int n  = b >> 8;
    const int c0 = (b & 255) * CHB_;
    const int lane = threadIdx.x & 63;
    const int wv = __builtin_amdgcn_readfirstlane(threadIdx.x >> 6);

    // ---- stage: wave w covers plane w>>2, chunks 3*(w&3) .. min(+3,11) ----
    {
        const int pl = wv >> 2;
        const int qh = wv & 3;
        const int base = (n * C_ + c0 + pl) * HW_;
        float* dst = &planes[pl][0];
        const int t0 = qh * 3, t1 = min(t0 + 3, 11);
        for (int t = t0; t < t1; ++t) {
            const int src = min(base + t * 256 + lane * 4, FM_WORDS - 4);
            ld_lds16(fm + src, dst + t * 256);
        }
    }
    asm volatile("s_waitcnt vmcnt(0)" ::: "memory");
    __syncthreads();

    int pi = lane / 7;
    int pj = lane - pi * 7;
    const bool active = lane < PP_;
    if (!active) { pi = 0; pj = 0; }          // idle lanes mirror lane 0

    const float* const p0l = &planes[0][0];
    const float* const p1l = &planes[1][0];
    const float* const p2l = &planes[2][0];
    const float* const p3l = &planes[3][0];

    const size_t obase = ((size_t)n * R_ * C_ + c0) * PP_ + lane;

    for (int r = wv; r < R_; r += WVS_) {
        const float4 roi = reinterpret_cast<const float4*>(rois)[n * R_ + r];
        const float y1 = roi.x * 0.0625f;
        const float x1 = roi.y * 0.0625f;
        const float y2 = (roi.x + roi.z) * 0.0625f;
        const float x2 = (roi.y + roi.w) * 0.0625f;
        const float sy = (y2 - y1) * (1.0f / 13.0f);
        const float sx = (x2 - x1) * (1.0f / 13.0f);

        const float py0 = y1 + sy * (float)(2 * pi);
        const float py1 = y1 + sy * (float)(2 * pi + 1);
        const float px0 = x1 + sx * (float)(2 * pj);
        const float px1 = x1 + sx * (float)(2 * pj + 1);

        int iy0; float wyA[2], wyB[3];
        axis_w(py0, py1, H_, iy0, wyA, wyB);
        int ix0; float wxA[2], wxB[3];
        axis_w(px0, px1, W_, ix0, wxA, wxB);
        const int gb = iy0 * W_ + ix0;        // <= 2499; reads reach <= 2601

        const float r0 = gather9(p0l + gb, wyA, wyB, wxA, wxB);
        const float r1 = gather9(p1l + gb, wyA, wyB, wxA, wxB);
        const float r2 = gather9(p2l + gb, wyA, wyB, wxA, wxB);
        const float r3 = gather9(p3l + gb, wyA, wyB, wxA, wxB);

        if (active) {
            float* __restrict__ po = out + obase + (size_t)r * C_ * PP_;
            po[0]       = r0;
            po[PP_]     = r1;
            po[2 * PP_] = r2;
            po[3 * PP_] = r3;
        }
    }
}

extern "C" void kernel_launch(void* const* d_in, const int* in_sizes, int n_in,
                              void* d_out, int out_size, void* d_ws, size_t ws_size,
                              hipStream_t stream) {
    const float* rois = (const float*)d_in[0];        // [4,256,4]
    const float* fm   = (const float*)d_in[1];        // [4,1024,50,50]
    float* out        = (float*)d_out;                // [4,256,1024,7,7]

    const int blocks = N_ * (C_ / CHB_);              // 4 * 256 = 1024
    roipool_kernel<<<blocks, 1024, 0, stream>>>(rois, fm, out);
}